// Round 1
// baseline (1163.484 us; speedup 1.0000x reference)
//
#include <hip/hip_runtime.h>

#define BT 256
#define HID 2048
#define NE 8
#define INTER 4096

typedef short short8 __attribute__((ext_vector_type(8)));
typedef float f32x4 __attribute__((ext_vector_type(4)));

__device__ inline unsigned short f2bf(float f){
  unsigned int u = __float_as_uint(f);
  u += 0x7fff + ((u >> 16) & 1);   // round-to-nearest-even
  return (unsigned short)(u >> 16);
}

// ---------------- routing: build per-expert token lists ----------------
// Semantics must match padded_weights.at[rows, sel].set(router_weights):
// duplicate expert within a token -> LAST router weight wins, single entry.
__global__ void routing_kernel(const int* __restrict__ sel, const float* __restrict__ rw,
                               int* counts, int* bases, int* tokl, float* wtl){
  __shared__ int cnt[NE]; __shared__ int bs[NE]; __shared__ int cur[NE];
  int t = threadIdx.x;
  if (t < NE) cnt[t] = 0;
  __syncthreads();
  int s0 = sel[2*t], s1 = sel[2*t+1];
  float w0 = rw[2*t], w1 = rw[2*t+1];
  bool dup = (s0 == s1);
  atomicAdd(&cnt[s1], 1);
  if (!dup) atomicAdd(&cnt[s0], 1);
  __syncthreads();
  if (t == 0){ int a = 0; for (int e = 0; e < NE; e++){ bs[e] = a; cur[e] = a; a += cnt[e]; } }
  __syncthreads();
  int slot = atomicAdd(&cur[s1], 1); tokl[slot] = t; wtl[slot] = w1;
  if (!dup){ slot = atomicAdd(&cur[s0], 1); tokl[slot] = t; wtl[slot] = w0; }
  if (t < NE){ counts[t] = cnt[t]; bases[t] = bs[t]; }
}

// ---------------- gemm1: up/gate = hs @ w13^T, cur = silu(up)*gate ----------------
// grid: (INTER/128 f-tiles, 4 m-tiles, 8 experts), block 256 (4 waves, 2x2 over 64x128)
__global__ __launch_bounds__(256) void gemm1_kernel(
    const float* __restrict__ hs, const float* __restrict__ w13,
    const int* __restrict__ counts, const int* __restrict__ bases,
    const int* __restrict__ tokl, unsigned short* __restrict__ cur)
{
  const int e = blockIdx.z;
  const int cnt = counts[e];
  const int mtile = blockIdx.y;
  if (mtile * 64 >= cnt) return;
  const int f0 = blockIdx.x * 128;
  const int base = bases[e];
  const int tid = threadIdx.x;

  __shared__ unsigned short As[64][72];       // padded stride 72 elem = 144 B (16B-aligned rows)
  __shared__ unsigned short Bs[2][128][72];

  const int lr = tid >> 4;      // 0..15
  const int c4 = tid & 15;      // 0..15, float4 column group

  const float* aptr[4];
  for (int p = 0; p < 4; p++){
    int row = p*16 + lr;
    int slot = mtile*64 + row; if (slot >= cnt) slot = cnt - 1;  // clamp; stores guarded later
    aptr[p] = hs + (size_t)tokl[base + slot] * HID + c4*4;
  }
  const size_t ebase = (size_t)e * 2 * INTER * HID;

  const int wv = tid >> 6, wm = wv >> 1, wn = wv & 1;
  const int lane = tid & 63;
  const int lrow = lane & 15;
  const int lko  = (lane >> 4) * 8;
  const int quad = lane >> 4;

  f32x4 acc[2][2][4];
  for (int s = 0; s < 2; s++) for (int mt = 0; mt < 2; mt++) for (int nt = 0; nt < 4; nt++)
    acc[s][mt][nt] = (f32x4){0.f, 0.f, 0.f, 0.f};

  for (int k0 = 0; k0 < HID; k0 += 64){
    for (int p = 0; p < 4; p++){
      float4 v = *(const float4*)(aptr[p] + k0);
      ushort4 b; b.x = f2bf(v.x); b.y = f2bf(v.y); b.z = f2bf(v.z); b.w = f2bf(v.w);
      *(ushort4*)&As[p*16 + lr][c4*4] = b;
    }
    for (int s = 0; s < 2; s++){
      for (int p = 0; p < 8; p++){
        int row = p*16 + lr;
        const float* bp = w13 + ebase + (size_t)(s*INTER + f0 + row) * HID + k0 + c4*4;
        float4 v = *(const float4*)bp;
        ushort4 b2; b2.x = f2bf(v.x); b2.y = f2bf(v.y); b2.z = f2bf(v.z); b2.w = f2bf(v.w);
        *(ushort4*)&Bs[s][row][c4*4] = b2;
      }
    }
    __syncthreads();
    for (int ks = 0; ks < 64; ks += 32){
      short8 a[2], b[2][4];
      for (int mt = 0; mt < 2; mt++)
        a[mt] = *(const short8*)&As[wm*32 + mt*16 + lrow][ks + lko];
      for (int s = 0; s < 2; s++)
        for (int nt = 0; nt < 4; nt++)
          b[s][nt] = *(const short8*)&Bs[s][wn*64 + nt*16 + lrow][ks + lko];
      for (int s = 0; s < 2; s++)
        for (int mt = 0; mt < 2; mt++)
          for (int nt = 0; nt < 4; nt++)
            acc[s][mt][nt] = __builtin_amdgcn_mfma_f32_16x16x32_bf16(
                a[mt], b[s][nt], acc[s][mt][nt], 0, 0, 0);
    }
    __syncthreads();
  }

  // epilogue: silu(up)*gate -> bf16 cur
  for (int mt = 0; mt < 2; mt++){
    for (int reg = 0; reg < 4; reg++){
      int m = mtile*64 + wm*32 + mt*16 + quad*4 + reg;
      if (m >= cnt) continue;
      size_t rowoff = (size_t)(base + m) * INTER;
      for (int nt = 0; nt < 4; nt++){
        int i = f0 + wn*64 + nt*16 + (lane & 15);
        float up   = acc[0][mt][nt][reg];
        float gate = acc[1][mt][nt][reg];
        float sv = up / (1.f + __expf(-up));
        cur[rowoff + i] = f2bf(sv * gate);
      }
    }
  }
}

// ---------------- gemm2: down = cur @ w2^T, out += weight * down ----------------
// grid: (HID/64 h-tiles, 4 m-tiles, 8 experts), block 256 (4 waves, 2x2 over 64x64)
__global__ __launch_bounds__(256) void gemm2_kernel(
    const unsigned short* __restrict__ cur, const float* __restrict__ w2,
    const int* __restrict__ counts, const int* __restrict__ bases,
    const int* __restrict__ tokl, const float* __restrict__ wtl,
    float* __restrict__ out)
{
  const int e = blockIdx.z;
  const int cnt = counts[e];
  const int mtile = blockIdx.y;
  if (mtile * 64 >= cnt) return;
  const int h0 = blockIdx.x * 64;
  const int base = bases[e];
  const int tid = threadIdx.x;

  __shared__ unsigned short As[64][72];
  __shared__ unsigned short Bs[64][72];

  const int r2 = tid >> 3, c8 = tid & 7;   // A: 16B (8 bf16) per thread, 2 passes
  const unsigned short* aptr[2];
  for (int p = 0; p < 2; p++){
    int row = p*32 + r2;
    int slot = mtile*64 + row; if (slot >= cnt) slot = cnt - 1;
    aptr[p] = cur + (size_t)(base + slot) * INTER + c8*8;
  }
  const int lr = tid >> 4, c4 = tid & 15;
  const size_t ebase = (size_t)e * HID * INTER;

  const int wv = tid >> 6, wm = wv >> 1, wn = wv & 1;
  const int lane = tid & 63;
  const int lrow = lane & 15, lko = (lane >> 4) * 8, quad = lane >> 4;

  f32x4 acc[2][2];
  for (int mt = 0; mt < 2; mt++) for (int nt = 0; nt < 2; nt++)
    acc[mt][nt] = (f32x4){0.f, 0.f, 0.f, 0.f};

  for (int k0 = 0; k0 < INTER; k0 += 64){
    for (int p = 0; p < 2; p++){
      uint4 v = *(const uint4*)(aptr[p] + k0);
      *(uint4*)&As[p*32 + r2][c8*8] = v;
    }
    for (int p = 0; p < 4; p++){
      int row = p*16 + lr;
      const float* bp = w2 + ebase + (size_t)(h0 + row) * INTER + k0 + c4*4;
      float4 v = *(const float4*)bp;
      ushort4 b2; b2.x = f2bf(v.x); b2.y = f2bf(v.y); b2.z = f2bf(v.z); b2.w = f2bf(v.w);
      *(ushort4*)&Bs[row][c4*4] = b2;
    }
    __syncthreads();
    for (int ks = 0; ks < 64; ks += 32){
      short8 a[2], b[2];
      for (int mt = 0; mt < 2; mt++) a[mt] = *(const short8*)&As[wm*32 + mt*16 + lrow][ks + lko];
      for (int nt = 0; nt < 2; nt++) b[nt] = *(const short8*)&Bs[wn*32 + nt*16 + lrow][ks + lko];
      for (int mt = 0; mt < 2; mt++) for (int nt = 0; nt < 2; nt++)
        acc[mt][nt] = __builtin_amdgcn_mfma_f32_16x16x32_bf16(a[mt], b[nt], acc[mt][nt], 0, 0, 0);
    }
    __syncthreads();
  }

  for (int mt = 0; mt < 2; mt++){
    for (int reg = 0; reg < 4; reg++){
      int m = mtile*64 + wm*32 + mt*16 + quad*4 + reg;
      if (m >= cnt) continue;
      int tk  = tokl[base + m];
      float w = wtl[base + m];
      for (int nt = 0; nt < 2; nt++){
        int h = h0 + wn*32 + nt*16 + (lane & 15);
        atomicAdd(&out[(size_t)tk * HID + h], w * acc[mt][nt][reg]);
      }
    }
  }
}

extern "C" void kernel_launch(void* const* d_in, const int* in_sizes, int n_in,
                              void* d_out, int out_size, void* d_ws, size_t ws_size,
                              hipStream_t stream){
  const float* hs  = (const float*)d_in[0];
  const int*   sel = (const int*)d_in[1];
  const float* rw  = (const float*)d_in[2];
  const float* w13 = (const float*)d_in[3];
  const float* w2  = (const float*)d_in[4];
  float* out = (float*)d_out;
  char* ws = (char*)d_ws;

  int* counts = (int*)ws;                  // 8
  int* bases  = counts + 8;                // 8
  int* tokl   = bases + 8;                 // 512
  float* wtl  = (float*)(tokl + 512);      // 512
  unsigned short* cur = (unsigned short*)(ws + 8192);  // 512*4096 bf16 = 4 MiB

  hipMemsetAsync(d_out, 0, (size_t)BT * HID * sizeof(float), stream);
  routing_kernel<<<1, 256, 0, stream>>>(sel, rw, counts, bases, tokl, wtl);
  dim3 g1(INTER/128, 4, NE);
  gemm1_kernel<<<g1, 256, 0, stream>>>(hs, w13, counts, bases, tokl, cur);
  dim3 g2(HID/64, 4, NE);
  gemm2_kernel<<<g2, 256, 0, stream>>>(cur, w2, counts, bases, tokl, wtl, out);
}